// Round 17
// baseline (286.923 us; speedup 1.0000x reference)
//
#include <hip/hip_runtime.h>

typedef unsigned short u16;
typedef __attribute__((ext_vector_type(8))) short bf16x8;
typedef __attribute__((ext_vector_type(4))) short bf16x4;
typedef __attribute__((ext_vector_type(4))) float f32x4;
typedef __attribute__((ext_vector_type(4))) u16 u16x4;

#define C1 0.18033688011112042f   // log2(e)/8  (folds the 1/sqrt(64) score scale)
#define NEGM (-64.0f*C1)          // fixed-max offset in exp2 domain

#define GLDS(g, l) __builtin_amdgcn_global_load_lds( \
    (const __attribute__((address_space(1))) void*)(g), \
    (__attribute__((address_space(3))) void*)(l), 16, 0, 0)

__device__ __forceinline__ float fastexp2(float x){
  float r;
  asm("v_exp_f32 %0, %1" : "=v"(r) : "v"(x));
  return r;
}

// packed f32x2 -> bf16x2 (low16 = bf16(x0), high16 = bf16(x1)), 1 VALU op
__device__ __forceinline__ unsigned cvtpk(float x0, float x1){
  unsigned r;
  asm("v_cvt_pk_bf16_f32 %0, %1, %2" : "=v"(r) : "v"(x0), "v"(x1));
  return r;
}

__device__ __forceinline__ bf16x4 pk4(float x0, float x1, float x2, float x3){
  union { unsigned u[2]; bf16x4 b; } o;
  o.u[0] = cvtpk(x0, x1);
  o.u[1] = cvtpk(x2, x3);
  return o.b;
}

__device__ __forceinline__ u16 f2bf(float x){
  unsigned u = __float_as_uint(x);
  u += 0x7fffu + ((u >> 16) & 1u);
  return (u16)(u >> 16);
}
__device__ __forceinline__ float bf2f(u16 h){ return __uint_as_float(((unsigned)h) << 16); }
__device__ __forceinline__ void fsplit(float x, u16 &h, u16 &l){
  h = f2bf(x);
  l = f2bf(x - bf2f(h));
}

// LDS slot swizzle (involution per row; empirically the low-conflict pattern).
__device__ __forceinline__ int swz(int slot, int r){
  return slot ^ (r & 7);
}

__device__ __forceinline__ bf16x8 frag(const bf16x8* lds, int r, int slot){
  return lds[r*8 + swz(slot, r)];
}

// b64 sub-fragment (A-operand of 16x16x16). Data is stored half-swapped by
// row-bit-3 (see k_proj T-writes) so quarter-wave lanes cover all 32 banks.
__device__ __forceinline__ bf16x4 frag64(const bf16x8* lds, int r, int slot, int half){
  return ((const bf16x4*)&lds[r*8 + swz(slot, r)])[half ^ ((r >> 3) & 1)];
}

// GLDS tile staging: linear LDS dest (wave chunk + lane*16), inverse-swizzled
// global source column -> LDS position swz(c) holds data column c (rule #21).
template<int ROWS>
__device__ __forceinline__ void stage_glds(bf16x8* lds, const u16* __restrict__ g,
                                           size_t row0, int ldg, int col0, int tid, int w){
#pragma unroll
  for (int p = 0; p < ROWS/32; ++p){
    int idx = p*256 + tid;
    int r = idx >> 3, slot = idx & 7;
    int ss = swz(slot, r);
    GLDS(g + (row0 + (size_t)r)*(size_t)ldg + col0 + ss*8, &lds[p*256 + (w<<6)]);
  }
}

// split-bf16 3-term product: X*Y ~= Xh*Yh + Xh*Yl + Xl*Yh   (fp32 accumulate)
__device__ __forceinline__ f32x4 mfma3(bf16x8 xh, bf16x8 xl, bf16x8 yh, bf16x8 yl, f32x4 c){
  c = __builtin_amdgcn_mfma_f32_16x16x32_bf16(xh, yh, c, 0, 0, 0);
  c = __builtin_amdgcn_mfma_f32_16x16x32_bf16(xh, yl, c, 0, 0, 0);
  c = __builtin_amdgcn_mfma_f32_16x16x32_bf16(xl, yh, c, 0, 0, 0);
  return c;
}

// ---- C/D-layout -> B-fragment relayout via 4-lane shuffle (hi-only) ----------
// (used only for the q-rebuild at iteration ends, 4x per kernel)
__device__ __forceinline__ void exchange_hi(const f32x4* X, int srcA, int srcB, bool sel_hi,
                                            bf16x8& oh0, bf16x8& oh1)
{
  unsigned hi[8];
#pragma unroll
  for (int a = 0; a < 4; ++a)
#pragma unroll
    for (int b0 = 0; b0 < 2; ++b0)
      hi[a*2+b0] = cvtpk(X[a][2*b0], X[a][2*b0+1]);
  unsigned OH[8];
#pragma unroll
  for (int f = 0; f < 8; ++f){
    const int t0 = (f>>2)*4 + (f&1);
    const int sl = ((f&3)>>1) ? srcB : srcA;
    unsigned h0 = (unsigned)__shfl((int)hi[t0],     sl, 64);
    unsigned h2 = (unsigned)__shfl((int)hi[t0 + 2], sl, 64);
    OH[f] = sel_hi ? h2 : h0;
  }
  union U { unsigned u[4]; bf16x8 b; };
  U a0, a1;
#pragma unroll
  for (int c = 0; c < 4; ++c){ a0.u[c]=OH[c]; a1.u[c]=OH[4+c]; }
  oh0=a0.b; oh1=a1.b;
}

// ---------------- elementwise convert (fused over q/k/v): fp32 -> bf16 hi ----------------
__global__ void __launch_bounds__(256) k_split3(
    const float* __restrict__ xq, const float* __restrict__ xk, const float* __restrict__ xv,
    u16* __restrict__ qh, u16* __restrict__ kh, u16* __restrict__ vh, int n4){
  const int which = blockIdx.y;
  const float* x = which == 0 ? xq : which == 1 ? xk : xv;
  u16* hh = which == 0 ? qh : which == 1 ? kh : vh;
  for (int i = blockIdx.x*256 + threadIdx.x; i < n4; i += gridDim.x*256){
    float4 v = ((const float4*)x)[i];
    u16x4 h;
    h[0] = f2bf(v.x); h[1] = f2bf(v.y); h[2] = f2bf(v.z); h[3] = f2bf(v.w);
    *(u16x4*)(hh + (size_t)i*4) = h;
  }
}

// ---------------- weight transpose + split (fused over 4 weights) ----------------
// wq, wk, wv: hi only. wo: hi + lo (out-proj stays 3-term for output precision).
__global__ void __launch_bounds__(256) k_wsplit4(
    const float* __restrict__ W0, const float* __restrict__ W1,
    const float* __restrict__ W2, const float* __restrict__ W3,
    u16* __restrict__ T0h, u16* __restrict__ T1h, u16* __restrict__ T2h,
    u16* __restrict__ T3h, u16* __restrict__ T3l){
  const int which = blockIdx.z;
  const float* W = which == 0 ? W0 : which == 1 ? W1 : which == 2 ? W2 : W3;
  u16* Th = which == 0 ? T0h : which == 1 ? T1h : which == 2 ? T2h : T3h;
  __shared__ float t[32][33];
  int tx = threadIdx.x & 31, ty = threadIdx.x >> 5;      // 32 x 8
  int n0 = blockIdx.x*32, k0 = blockIdx.y*32;
#pragma unroll
  for (int i = 0; i < 4; ++i)
    t[ty + 8*i][tx] = W[(size_t)(k0 + ty + 8*i)*1024 + n0 + tx];
  __syncthreads();
#pragma unroll
  for (int i = 0; i < 4; ++i){
    int n = n0 + ty + 8*i, k = k0 + tx;
    if (which == 3){
      u16 a, b; fsplit(t[tx][ty + 8*i], a, b);
      Th[(size_t)n*1024 + k] = a;
      T3l[(size_t)n*1024 + k] = b;
    } else {
      Th[(size_t)n*1024 + k] = f2bf(t[tx][ty + 8*i]);
    }
  }
}

// ---------------- projection / output GEMM ----------------
// C(4096x1024) = A(4096x1024) * Bt^T (+bias), tile 128x64, 4 waves x (32 rows x 64 cols)
// Staging via global_load_lds (linear dest + inverse-swizzled source).
// SPLIT=false: 1-term hi*hi GEMM (Q/K/V projections). SPLIT=true: 3-term (out-proj).
// MODE 0: Q  -> LN, natural head-major write (hi only)
// MODE 1: K  -> LN, natural + transposed writes (hi only; half-swapped T)
// MODE 2: V  -> transposed hi-only write (half-swapped)
// MODE 3: out-> fp32 write to d_out
template<int MODE, bool SPLIT>
__global__ void __launch_bounds__(256, 3) k_proj(
    const u16* __restrict__ Ah, const u16* __restrict__ Al,
    const u16* __restrict__ Bh, const u16* __restrict__ Bl,
    const float* __restrict__ bias, const float* __restrict__ gamma, const float* __restrict__ beta,
    u16* __restrict__ Nh,
    u16* __restrict__ Th,
    float* __restrict__ Fo)
{
  __shared__ bf16x8 sAh[128*8], sBh[64*8];
  __shared__ bf16x8 sAl[SPLIT ? 128*8 : 1], sBl[SPLIT ? 64*8 : 1];
  const int tid = threadIdx.x, lane = tid & 63, w = tid >> 6;
  const int cl = lane & 15, gq = lane >> 4;
  const int nt = blockIdx.x, mt = blockIdx.y;
  f32x4 acc[2][4] = {};
  for (int kt = 0; kt < 16; ++kt){
    __syncthreads();
    stage_glds<128>(sAh, Ah, (size_t)mt*128, 1024, kt*64, tid, w);
    stage_glds<64>(sBh, Bh, (size_t)nt*64, 1024, kt*64, tid, w);
    if constexpr (SPLIT){
      stage_glds<128>(sAl, Al, (size_t)mt*128, 1024, kt*64, tid, w);
      stage_glds<64>(sBl, Bl, (size_t)nt*64, 1024, kt*64, tid, w);
    }
    __syncthreads();
#pragma unroll
    for (int ks = 0; ks < 2; ++ks){
      const int slot = ks*4 + gq;
      bf16x8 ah0 = frag(sAh, w*32 + cl, slot);
      bf16x8 ah1 = frag(sAh, w*32 + 16 + cl, slot);
      if constexpr (SPLIT){
        bf16x8 al0 = frag(sAl, w*32 + cl, slot);
        bf16x8 al1 = frag(sAl, w*32 + 16 + cl, slot);
#pragma unroll
        for (int f = 0; f < 4; ++f){
          bf16x8 bh_ = frag(sBh, f*16 + cl, slot);
          bf16x8 bl_ = frag(sBl, f*16 + cl, slot);
          acc[0][f] = mfma3(ah0, al0, bh_, bl_, acc[0][f]);
          acc[1][f] = mfma3(ah1, al1, bh_, bl_, acc[1][f]);
        }
      } else {
#pragma unroll
        for (int f = 0; f < 4; ++f){
          bf16x8 bh_ = frag(sBh, f*16 + cl, slot);
          acc[0][f] = __builtin_amdgcn_mfma_f32_16x16x32_bf16(ah0, bh_, acc[0][f], 0, 0, 0);
          acc[1][f] = __builtin_amdgcn_mfma_f32_16x16x32_bf16(ah1, bh_, acc[1][f], 0, 0, 0);
        }
      }
    }
  }
  float bv[4];
#pragma unroll
  for (int f = 0; f < 4; ++f) bv[f] = bias[nt*64 + f*16 + cl];
  float gm[4], bt[4];
  if constexpr (MODE <= 1){
#pragma unroll
    for (int f = 0; f < 4; ++f){ gm[f] = gamma[f*16 + cl]; bt[f] = beta[f*16 + cl]; }
  }
#pragma unroll
  for (int mi = 0; mi < 2; ++mi){
    float v[4][4];
#pragma unroll
    for (int f = 0; f < 4; ++f)
#pragma unroll
      for (int r = 0; r < 4; ++r) v[f][r] = acc[mi][f][r] + bv[f];
    if constexpr (MODE <= 1){
#pragma unroll
      for (int r = 0; r < 4; ++r){
        float s1 = v[0][r] + v[1][r] + v[2][r] + v[3][r];
        float s2 = v[0][r]*v[0][r] + v[1][r]*v[1][r] + v[2][r]*v[2][r] + v[3][r]*v[3][r];
#pragma unroll
        for (int d = 1; d < 16; d <<= 1){ s1 += __shfl_xor(s1, d); s2 += __shfl_xor(s2, d); }
        float mu = s1 * (1.f/64.f);
        float var = s2 * (1.f/64.f) - mu*mu;
        float rs = rsqrtf(var + 1e-5f);
#pragma unroll
        for (int f = 0; f < 4; ++f) v[f][r] = (v[f][r] - mu)*rs*gm[f] + bt[f];
      }
    }
    const int mrow = mt*128 + w*32 + mi*16 + gq*4;   // + r
    if constexpr (MODE == 3){
#pragma unroll
      for (int f = 0; f < 4; ++f)
#pragma unroll
        for (int r = 0; r < 4; ++r)
          Fo[(size_t)(mrow + r)*1024 + nt*64 + f*16 + cl] = v[f][r];
    } else {
      const int b = mrow >> 11, srow = mrow & 2047;
      const size_t hb = (size_t)(b*16 + nt);          // head-major (b*16 + head)
      if constexpr (MODE <= 1){                       // natural write, hi only
#pragma unroll
        for (int f = 0; f < 4; ++f)
#pragma unroll
          for (int r = 0; r < 4; ++r)
            Nh[(hb*2048 + srow + r)*64 + f*16 + cl] = f2bf(v[f][r]);
      }
      if constexpr (MODE == 1 || MODE == 2){          // transposed write, hi only
        const int srow_sw = srow ^ (((cl >> 3) & 1) << 2);
#pragma unroll
        for (int f = 0; f < 4; ++f){
          u16x4 h4;
#pragma unroll
          for (int r = 0; r < 4; ++r) h4[r] = f2bf(v[f][r]);
          *(u16x4*)(Th + (hb*64 + f*16 + cl)*2048 + srow_sw) = h4;
        }
      }
    }
  }
}

// ---------------- fused Hopfield attention: all 4 iterations in one launch ----------------
// Block = 256 thr (4 waves), owns (bh, 128 q rows); each wave owns TWO 16-row
// q-groups so every K/T fragment read from LDS feeds both (the LDS-read pipe was
// the binding resource at 82% — sharing halves it; the kernel is now throughput-
// bound, not latency-bound as in the round-4 attempt). Grid 512 = 2 blocks/CU.
// FIXED-MAX softmax; Q/K/P/T all bf16 hi-only; PV + denominator via 16x16x16
// MFMA on the native QK C/D fragment (no cross-lane P relayout); T read as b64
// sub-frags with half-swapped storage. 1 barrier/step, GLDS double-buffered.
__global__ void __launch_bounds__(256, 2) k_hopfield(
    const u16* __restrict__ Qh,
    const u16* __restrict__ Kh,
    const u16* __restrict__ Kth,
    const u16* __restrict__ Vth,
    u16* __restrict__ Oh, u16* __restrict__ Ol)
{
  __shared__ bf16x8 sKh[2][512], sTh[2][512];
  const int tid = threadIdx.x, lane = tid & 63, w = tid >> 6;   // w = 0..3
  const int cl = lane & 15, gq = lane >> 4;
  int flat = blockIdx.x;
  flat = (flat & 7)*64 + (flat >> 3);              // XCD swizzle (512 % 8 == 0: bijective)
  const int bh = flat >> 4, qt = flat & 15;
  const size_t base = (size_t)bh * (2048*64);

  // staging: thread stages slots tid and tid+256 of each 64x64 tile (rows sr, sr+32),
  // source column pre-swizzled so the lane-linear LDS write lands swizzled.
  const int sr = tid >> 3, ss = swz(tid & 7, sr);  // (sr+32)&7 == sr&7 -> same ss
  const size_t offK = base + (size_t)sr*64 + ss*8;      // + kt*4096 ; +2048 for row sr+32
  const size_t offT = base + (size_t)sr*2048 + ss*8;    // + kt*64   ; +65536 for row sr+32
  const int wslot = w << 6;                             // wave chunk (bf16x8 units)

  // q fragments (B-operand layout, hi-only), 2 q-groups, live across all 4 iterations
  bf16x8 qfh[2][2];
#pragma unroll
  for (int qg = 0; qg < 2; ++qg){
    const int q = qt*128 + w*32 + qg*16 + cl;
#pragma unroll
    for (int ks = 0; ks < 2; ++ks)
      qfh[qg][ks] = *(const bf16x8*)(Qh + base + (size_t)q*64 + ks*32 + gq*8);
  }

  const int srcA = cl + ((gq & 1) << 5);   // shuffle source lanes for exchange_hi()
  const int srcB = srcA + 16;
  const bool sel_hi = gq >= 2;             // dest-side select: t-offset = 2*(gq>>1)

  const bf16x4 ones = {(short)0x3F80, (short)0x3F80, (short)0x3F80, (short)0x3F80};
  f32x4 accL[2] = {};                      // P column-sums per q-group
  f32x4 accO[2][4] = {};

  // prologue: stage tile 0 (it=0 -> T source is Kt)
  GLDS(Kh  + offK,        &sKh[0][wslot]);
  GLDS(Kh  + offK + 2048, &sKh[0][wslot + 256]);
  GLDS(Kth + offT,         &sTh[0][wslot]);
  GLDS(Kth + offT + 65536, &sTh[0][wslot + 256]);
  __syncthreads();

#pragma unroll 2
  for (int t = 0; t < 128; ++t){
    const int cur = t & 1, kt = t & 31;
    if (t < 127){
      const int nt_ = t + 1, nb = nt_ & 1, nit = nt_ >> 5, nkt = nt_ & 31;
      const u16* th = (nit < 3) ? Kth : Vth;
      const size_t oK = offK + (size_t)nkt*4096;
      const size_t oT = offT + (size_t)nkt*64;
      GLDS(Kh + oK,        &sKh[nb][wslot]);
      GLDS(Kh + oK + 2048, &sKh[nb][wslot + 256]);
      GLDS(th + oT,         &sTh[nb][wslot]);
      GLDS(th + oT + 65536, &sTh[nb][wslot + 256]);
    }
    // ---- QK^T: St[kv][q], each K fragment feeds both q-groups ----
    f32x4 S[2][4] = {};
    __builtin_amdgcn_s_setprio(1);
#pragma unroll
    for (int ks = 0; ks < 2; ++ks){
      const int slot = ks*4 + gq;
#pragma unroll
      for (int i = 0; i < 4; ++i){
        bf16x8 kh_ = frag(&sKh[cur][0], i*16 + cl, slot);
        S[0][i] = __builtin_amdgcn_mfma_f32_16x16x32_bf16(kh_, qfh[0][ks], S[0][i], 0, 0, 0);
        S[1][i] = __builtin_amdgcn_mfma_f32_16x16x32_bf16(kh_, qfh[1][ks], S[1][i], 0, 0, 0);
      }
    }
    __builtin_amdgcn_s_setprio(0);
    // ---- fixed-max softmax + pack (per q-group) ----
    bf16x4 pf[2][4];
#pragma unroll
    for (int qg = 0; qg < 2; ++qg){
#pragma unroll
      for (int i = 0; i < 4; ++i)
#pragma unroll
        for (int r = 0; r < 4; ++r)
          S[qg][i][r] = fastexp2(__builtin_fmaf(S[qg][i][r], C1, NEGM));
#pragma unroll
      for (int a = 0; a < 4; ++a)
        pf[qg][a] = pk4(S[qg][a][0], S[qg][a][1], S[qg][a][2], S[qg][a][3]);
    }
    // ---- denominators + PV via 16x16x16; each T fragment feeds both q-groups ----
    __builtin_amdgcn_s_setprio(1);
#pragma unroll
    for (int a = 0; a < 4; ++a){
      accL[0] = __builtin_amdgcn_mfma_f32_16x16x16bf16_1k(ones, pf[0][a], accL[0], 0, 0, 0);
      accL[1] = __builtin_amdgcn_mfma_f32_16x16x16bf16_1k(ones, pf[1][a], accL[1], 0, 0, 0);
    }
#pragma unroll
    for (int db = 0; db < 4; ++db)
#pragma unroll
      for (int a = 0; a < 4; ++a){
        bf16x4 vh_ = frag64(&sTh[cur][0], db*16 + cl, 2*a + (gq>>1), gq&1);
        accO[0][db] = __builtin_amdgcn_mfma_f32_16x16x16bf16_1k(vh_, pf[0][a], accO[0][db], 0, 0, 0);
        accO[1][db] = __builtin_amdgcn_mfma_f32_16x16x16bf16_1k(vh_, pf[1][a], accO[1][db], 0, 0, 0);
      }
    __builtin_amdgcn_s_setprio(0);
    // ---- iteration epilogue ----
    if (kt == 31){
#pragma unroll
      for (int qg = 0; qg < 2; ++qg){
        const float inv = 1.f / accL[qg][0];   // accL rows identical: full Σp for q=cl
        f32x4 vals[4];
#pragma unroll
        for (int db = 0; db < 4; ++db)
#pragma unroll
          for (int r = 0; r < 4; ++r) vals[db][r] = accO[qg][db][r]*inv;
        if (t < 127){
          exchange_hi(vals, srcA, srcB, sel_hi, qfh[qg][0], qfh[qg][1]);
          accL[qg] = f32x4{0,0,0,0};
#pragma unroll
          for (int db = 0; db < 4; ++db) accO[qg][db] = f32x4{0,0,0,0};
        } else {
          const int b = bh >> 4, h = bh & 15;
          const int q = qt*128 + w*32 + qg*16 + cl;
          const size_t row = (size_t)b*2048 + q;
#pragma unroll
          for (int db = 0; db < 4; ++db){
            u16x4 h4, l4;
#pragma unroll
            for (int r = 0; r < 4; ++r){ u16 a_, b_; fsplit(vals[db][r], a_, b_); h4[r] = a_; l4[r] = b_; }
            size_t ix = row*1024 + h*64 + db*16 + gq*4;
            *(u16x4*)(Oh + ix) = h4;
            *(u16x4*)(Ol + ix) = l4;
          }
        }
      }
    }
    __syncthreads();
  }
}

extern "C" void kernel_launch(void* const* d_in, const int* in_sizes, int n_in,
                              void* d_out, int out_size, void* d_ws, size_t ws_size,
                              hipStream_t stream) {
  (void)in_sizes; (void)n_in; (void)out_size; (void)ws_size;
  const float* query = (const float*)d_in[0];
  const float* key   = (const float*)d_in[1];
  const float* value = (const float*)d_in[2];
  const float* Wq = (const float*)d_in[3];
  const float* bq = (const float*)d_in[4];
  const float* Wk = (const float*)d_in[5];
  const float* bk = (const float*)d_in[6];
  const float* Wv = (const float*)d_in[7];
  const float* bv = (const float*)d_in[8];
  const float* Wo = (const float*)d_in[9];
  const float* bo = (const float*)d_in[10];
  const float* gamma = (const float*)d_in[11];
  const float* beta  = (const float*)d_in[12];
  float* out = (float*)d_out;

  char* ws = (char*)d_ws;
  const size_t MB = 1024*1024;
  u16* inq_h = (u16*)(ws + 0*MB),  *inq_l = (u16*)(ws + 8*MB);
  u16* ink_h = (u16*)(ws + 16*MB);
  u16* inv_h = (u16*)(ws + 32*MB);
  u16* wq_h = (u16*)(ws + 48*MB);
  u16* wk_h = (u16*)(ws + 52*MB);
  u16* wv_h = (u16*)(ws + 56*MB);
  u16* wo_h = (u16*)(ws + 60*MB), *wo_l = (u16*)(ws + 62*MB);
  u16* Qh  = (u16*)(ws + 64*MB);
  u16* Kh  = (u16*)(ws + 80*MB);
  u16* Kth = (u16*)(ws + 96*MB);
  u16* Vth = (u16*)(ws + 112*MB);
  u16* Oh = inq_h, *Ol = inq_l;    // reuse: inq dead after proj<0>

  const int n4 = 4096*1024/4;
  k_split3<<<dim3(1024, 3), dim3(256), 0, stream>>>(query, key, value,
                                                    inq_h, ink_h, inv_h, n4);
  k_wsplit4<<<dim3(32,32,4), dim3(256), 0, stream>>>(Wq, Wk, Wv, Wo,
                                                     wq_h, wk_h, wv_h, wo_h, wo_l);

  k_proj<0,false><<<dim3(16,32), dim3(256), 0, stream>>>(inq_h, nullptr, wq_h, nullptr, bq, gamma, beta,
                                                         Qh, nullptr, nullptr);
  k_proj<1,false><<<dim3(16,32), dim3(256), 0, stream>>>(ink_h, nullptr, wk_h, nullptr, bk, gamma, beta,
                                                         Kh, Kth, nullptr);
  k_proj<2,false><<<dim3(16,32), dim3(256), 0, stream>>>(inv_h, nullptr, wv_h, nullptr, bv, nullptr, nullptr,
                                                         nullptr, Vth, nullptr);

  k_hopfield<<<dim3(512), dim3(256), 0, stream>>>(Qh, Kh, Kth, Vth, Oh, Ol);

  k_proj<3,true><<<dim3(16,32), dim3(256), 0, stream>>>(Oh, Ol, wo_h, wo_l, bo, nullptr, nullptr,
                                                        nullptr, nullptr, out);
}

// Round 18
// 270.800 us; speedup vs baseline: 1.0595x; 1.0595x over previous
//
#include <hip/hip_runtime.h>

typedef unsigned short u16;
typedef __attribute__((ext_vector_type(8))) short bf16x8;
typedef __attribute__((ext_vector_type(4))) short bf16x4;
typedef __attribute__((ext_vector_type(4))) float f32x4;
typedef __attribute__((ext_vector_type(4))) u16 u16x4;

#define C1 0.18033688011112042f   // log2(e)/8  (folds the 1/sqrt(64) score scale)
#define NEGM (-64.0f*C1)          // fixed-max offset in exp2 domain

#define GLDS(g, l) __builtin_amdgcn_global_load_lds( \
    (const __attribute__((address_space(1))) void*)(g), \
    (__attribute__((address_space(3))) void*)(l), 16, 0, 0)

__device__ __forceinline__ float fastexp2(float x){
  float r;
  asm("v_exp_f32 %0, %1" : "=v"(r) : "v"(x));
  return r;
}

// packed f32x2 -> bf16x2 (low16 = bf16(x0), high16 = bf16(x1)), 1 VALU op
__device__ __forceinline__ unsigned cvtpk(float x0, float x1){
  unsigned r;
  asm("v_cvt_pk_bf16_f32 %0, %1, %2" : "=v"(r) : "v"(x0), "v"(x1));
  return r;
}

__device__ __forceinline__ bf16x4 pk4(float x0, float x1, float x2, float x3){
  union { unsigned u[2]; bf16x4 b; } o;
  o.u[0] = cvtpk(x0, x1);
  o.u[1] = cvtpk(x2, x3);
  return o.b;
}

__device__ __forceinline__ u16 f2bf(float x){
  unsigned u = __float_as_uint(x);
  u += 0x7fffu + ((u >> 16) & 1u);
  return (u16)(u >> 16);
}
__device__ __forceinline__ float bf2f(u16 h){ return __uint_as_float(((unsigned)h) << 16); }
__device__ __forceinline__ void fsplit(float x, u16 &h, u16 &l){
  h = f2bf(x);
  l = f2bf(x - bf2f(h));
}

// LDS slot swizzle (involution per row; empirically the low-conflict pattern).
__device__ __forceinline__ int swz(int slot, int r){
  return slot ^ (r & 7);
}

__device__ __forceinline__ bf16x8 frag(const bf16x8* lds, int r, int slot){
  return lds[r*8 + swz(slot, r)];
}

// b64 sub-fragment (A-operand of 16x16x16). Data is stored half-swapped by
// row-bit-3 (see T-writes) so quarter-wave lanes cover all 32 banks.
__device__ __forceinline__ bf16x4 frag64(const bf16x8* lds, int r, int slot, int half){
  return ((const bf16x4*)&lds[r*8 + swz(slot, r)])[half ^ ((r >> 3) & 1)];
}

// GLDS tile staging: linear LDS dest (wave chunk + lane*16), inverse-swizzled
// global source column -> LDS position swz(c) holds data column c (rule #21).
template<int ROWS>
__device__ __forceinline__ void stage_glds(bf16x8* lds, const u16* __restrict__ g,
                                           size_t row0, int ldg, int col0, int tid, int w){
#pragma unroll
  for (int p = 0; p < ROWS/32; ++p){
    int idx = p*256 + tid;
    int r = idx >> 3, slot = idx & 7;
    int ss = swz(slot, r);
    GLDS(g + (row0 + (size_t)r)*(size_t)ldg + col0 + ss*8, &lds[p*256 + (w<<6)]);
  }
}

// split-bf16 3-term product: X*Y ~= Xh*Yh + Xh*Yl + Xl*Yh   (fp32 accumulate)
__device__ __forceinline__ f32x4 mfma3(bf16x8 xh, bf16x8 xl, bf16x8 yh, bf16x8 yl, f32x4 c){
  c = __builtin_amdgcn_mfma_f32_16x16x32_bf16(xh, yh, c, 0, 0, 0);
  c = __builtin_amdgcn_mfma_f32_16x16x32_bf16(xh, yl, c, 0, 0, 0);
  c = __builtin_amdgcn_mfma_f32_16x16x32_bf16(xl, yh, c, 0, 0, 0);
  return c;
}

// ---- C/D-layout -> B-fragment relayout via 4-lane shuffle (hi-only) ----------
// (used only for the q-rebuild at iteration ends, 4x per kernel)
__device__ __forceinline__ void exchange_hi(const f32x4* X, int srcA, int srcB, bool sel_hi,
                                            bf16x8& oh0, bf16x8& oh1)
{
  unsigned hi[8];
#pragma unroll
  for (int a = 0; a < 4; ++a)
#pragma unroll
    for (int b0 = 0; b0 < 2; ++b0)
      hi[a*2+b0] = cvtpk(X[a][2*b0], X[a][2*b0+1]);
  unsigned OH[8];
#pragma unroll
  for (int f = 0; f < 8; ++f){
    const int t0 = (f>>2)*4 + (f&1);
    const int sl = ((f&3)>>1) ? srcB : srcA;
    unsigned h0 = (unsigned)__shfl((int)hi[t0],     sl, 64);
    unsigned h2 = (unsigned)__shfl((int)hi[t0 + 2], sl, 64);
    OH[f] = sel_hi ? h2 : h0;
  }
  union U { unsigned u[4]; bf16x8 b; };
  U a0, a1;
#pragma unroll
  for (int c = 0; c < 4; ++c){ a0.u[c]=OH[c]; a1.u[c]=OH[4+c]; }
  oh0=a0.b; oh1=a1.b;
}

// ---------------- elementwise convert (fused over q/k/v): fp32 -> bf16 hi ----------------
__global__ void __launch_bounds__(256) k_split3(
    const float* __restrict__ xq, const float* __restrict__ xk, const float* __restrict__ xv,
    u16* __restrict__ qh, u16* __restrict__ kh, u16* __restrict__ vh, int n4){
  const int which = blockIdx.y;
  const float* x = which == 0 ? xq : which == 1 ? xk : xv;
  u16* hh = which == 0 ? qh : which == 1 ? kh : vh;
  for (int i = blockIdx.x*256 + threadIdx.x; i < n4; i += gridDim.x*256){
    float4 v = ((const float4*)x)[i];
    u16x4 h;
    h[0] = f2bf(v.x); h[1] = f2bf(v.y); h[2] = f2bf(v.z); h[3] = f2bf(v.w);
    *(u16x4*)(hh + (size_t)i*4) = h;
  }
}

// ---------------- weight transpose + split (fused over 4 weights) ----------------
// wq, wk, wv: hi only. wo: hi + lo (out-proj stays 3-term for output precision).
__global__ void __launch_bounds__(256) k_wsplit4(
    const float* __restrict__ W0, const float* __restrict__ W1,
    const float* __restrict__ W2, const float* __restrict__ W3,
    u16* __restrict__ T0h, u16* __restrict__ T1h, u16* __restrict__ T2h,
    u16* __restrict__ T3h, u16* __restrict__ T3l){
  const int which = blockIdx.z;
  const float* W = which == 0 ? W0 : which == 1 ? W1 : which == 2 ? W2 : W3;
  u16* Th = which == 0 ? T0h : which == 1 ? T1h : which == 2 ? T2h : T3h;
  __shared__ float t[32][33];
  int tx = threadIdx.x & 31, ty = threadIdx.x >> 5;      // 32 x 8
  int n0 = blockIdx.x*32, k0 = blockIdx.y*32;
#pragma unroll
  for (int i = 0; i < 4; ++i)
    t[ty + 8*i][tx] = W[(size_t)(k0 + ty + 8*i)*1024 + n0 + tx];
  __syncthreads();
#pragma unroll
  for (int i = 0; i < 4; ++i){
    int n = n0 + ty + 8*i, k = k0 + tx;
    if (which == 3){
      u16 a, b; fsplit(t[tx][ty + 8*i], a, b);
      Th[(size_t)n*1024 + k] = a;
      T3l[(size_t)n*1024 + k] = b;
    } else {
      Th[(size_t)n*1024 + k] = f2bf(t[tx][ty + 8*i]);
    }
  }
}

// ---------------- fused Q/K/V projection GEMMs (one dispatch) ----------------
// blockIdx.z = mode: 0=Q (LN, natural write), 1=K (LN, natural + transposed),
// 2=V (transposed only). GEMM body identical across modes (1-term hi*hi,
// tile 128x64, GLDS staging); mode branch is block-uniform, epilogue only.
__global__ void __launch_bounds__(256, 3) k_proj3(
    const u16* __restrict__ Aq, const u16* __restrict__ Ak, const u16* __restrict__ Av,
    const u16* __restrict__ Bq, const u16* __restrict__ Bk, const u16* __restrict__ Bv,
    const float* __restrict__ bq, const float* __restrict__ bk, const float* __restrict__ bv_,
    const float* __restrict__ gamma, const float* __restrict__ beta,
    u16* __restrict__ Qh, u16* __restrict__ Kh,
    u16* __restrict__ Kth, u16* __restrict__ Vth)
{
  __shared__ bf16x8 sAh[128*8], sBh[64*8];
  const int mode = blockIdx.z;
  const u16* Ah = mode == 0 ? Aq : mode == 1 ? Ak : Av;
  const u16* Bh = mode == 0 ? Bq : mode == 1 ? Bk : Bv;
  const float* bias = mode == 0 ? bq : mode == 1 ? bk : bv_;
  const int tid = threadIdx.x, lane = tid & 63, w = tid >> 6;
  const int cl = lane & 15, gq = lane >> 4;
  const int nt = blockIdx.x, mt = blockIdx.y;
  f32x4 acc[2][4] = {};
  for (int kt = 0; kt < 16; ++kt){
    __syncthreads();
    stage_glds<128>(sAh, Ah, (size_t)mt*128, 1024, kt*64, tid, w);
    stage_glds<64>(sBh, Bh, (size_t)nt*64, 1024, kt*64, tid, w);
    __syncthreads();
#pragma unroll
    for (int ks = 0; ks < 2; ++ks){
      const int slot = ks*4 + gq;
      bf16x8 ah0 = frag(sAh, w*32 + cl, slot);
      bf16x8 ah1 = frag(sAh, w*32 + 16 + cl, slot);
#pragma unroll
      for (int f = 0; f < 4; ++f){
        bf16x8 bh_ = frag(sBh, f*16 + cl, slot);
        acc[0][f] = __builtin_amdgcn_mfma_f32_16x16x32_bf16(ah0, bh_, acc[0][f], 0, 0, 0);
        acc[1][f] = __builtin_amdgcn_mfma_f32_16x16x32_bf16(ah1, bh_, acc[1][f], 0, 0, 0);
      }
    }
  }
  float bv[4];
#pragma unroll
  for (int f = 0; f < 4; ++f) bv[f] = bias[nt*64 + f*16 + cl];
  float gm[4], bt[4];
  if (mode <= 1){
#pragma unroll
    for (int f = 0; f < 4; ++f){ gm[f] = gamma[f*16 + cl]; bt[f] = beta[f*16 + cl]; }
  }
#pragma unroll
  for (int mi = 0; mi < 2; ++mi){
    float v[4][4];
#pragma unroll
    for (int f = 0; f < 4; ++f)
#pragma unroll
      for (int r = 0; r < 4; ++r) v[f][r] = acc[mi][f][r] + bv[f];
    if (mode <= 1){
#pragma unroll
      for (int r = 0; r < 4; ++r){
        float s1 = v[0][r] + v[1][r] + v[2][r] + v[3][r];
        float s2 = v[0][r]*v[0][r] + v[1][r]*v[1][r] + v[2][r]*v[2][r] + v[3][r]*v[3][r];
#pragma unroll
        for (int d = 1; d < 16; d <<= 1){ s1 += __shfl_xor(s1, d); s2 += __shfl_xor(s2, d); }
        float mu = s1 * (1.f/64.f);
        float var = s2 * (1.f/64.f) - mu*mu;
        float rs = rsqrtf(var + 1e-5f);
#pragma unroll
        for (int f = 0; f < 4; ++f) v[f][r] = (v[f][r] - mu)*rs*gm[f] + bt[f];
      }
    }
    const int mrow = mt*128 + w*32 + mi*16 + gq*4;   // + r
    const int b = mrow >> 11, srow = mrow & 2047;
    const size_t hb = (size_t)(b*16 + nt);            // head-major (b*16 + head)
    if (mode <= 1){                                   // natural write, hi only
      u16* Nh = mode == 0 ? Qh : Kh;
#pragma unroll
      for (int f = 0; f < 4; ++f)
#pragma unroll
        for (int r = 0; r < 4; ++r)
          Nh[(hb*2048 + srow + r)*64 + f*16 + cl] = f2bf(v[f][r]);
    }
    if (mode >= 1){                                   // transposed write, hi only
      u16* Th = mode == 1 ? Kth : Vth;
      const int srow_sw = srow ^ (((cl >> 3) & 1) << 2);
#pragma unroll
      for (int f = 0; f < 4; ++f){
        u16x4 h4;
#pragma unroll
        for (int r = 0; r < 4; ++r) h4[r] = f2bf(v[f][r]);
        *(u16x4*)(Th + (hb*64 + f*16 + cl)*2048 + srow_sw) = h4;
      }
    }
  }
}

// ---------------- output projection GEMM (3-term split) ----------------
__global__ void __launch_bounds__(256, 3) k_projo(
    const u16* __restrict__ Ah, const u16* __restrict__ Al,
    const u16* __restrict__ Bh, const u16* __restrict__ Bl,
    const float* __restrict__ bias,
    float* __restrict__ Fo)
{
  __shared__ bf16x8 sAh[128*8], sAl[128*8], sBh[64*8], sBl[64*8];
  const int tid = threadIdx.x, lane = tid & 63, w = tid >> 6;
  const int cl = lane & 15, gq = lane >> 4;
  const int nt = blockIdx.x, mt = blockIdx.y;
  f32x4 acc[2][4] = {};
  for (int kt = 0; kt < 16; ++kt){
    __syncthreads();
    stage_glds<128>(sAh, Ah, (size_t)mt*128, 1024, kt*64, tid, w);
    stage_glds<64>(sBh, Bh, (size_t)nt*64, 1024, kt*64, tid, w);
    stage_glds<128>(sAl, Al, (size_t)mt*128, 1024, kt*64, tid, w);
    stage_glds<64>(sBl, Bl, (size_t)nt*64, 1024, kt*64, tid, w);
    __syncthreads();
#pragma unroll
    for (int ks = 0; ks < 2; ++ks){
      const int slot = ks*4 + gq;
      bf16x8 ah0 = frag(sAh, w*32 + cl, slot);
      bf16x8 ah1 = frag(sAh, w*32 + 16 + cl, slot);
      bf16x8 al0 = frag(sAl, w*32 + cl, slot);
      bf16x8 al1 = frag(sAl, w*32 + 16 + cl, slot);
#pragma unroll
      for (int f = 0; f < 4; ++f){
        bf16x8 bh_ = frag(sBh, f*16 + cl, slot);
        bf16x8 bl_ = frag(sBl, f*16 + cl, slot);
        acc[0][f] = mfma3(ah0, al0, bh_, bl_, acc[0][f]);
        acc[1][f] = mfma3(ah1, al1, bh_, bl_, acc[1][f]);
      }
    }
  }
  float bv[4];
#pragma unroll
  for (int f = 0; f < 4; ++f) bv[f] = bias[nt*64 + f*16 + cl];
#pragma unroll
  for (int mi = 0; mi < 2; ++mi){
    const int mrow = mt*128 + w*32 + mi*16 + gq*4;
#pragma unroll
    for (int f = 0; f < 4; ++f)
#pragma unroll
      for (int r = 0; r < 4; ++r)
        Fo[(size_t)(mrow + r)*1024 + nt*64 + f*16 + cl] = acc[mi][f][r] + bv[f];
  }
}

// ---------------- fused Hopfield attention: all 4 iterations in one launch ----------------
// (round-16 structure, verbatim: 8 waves x 16 q — the measured optimum on the
// occupancy<->LDS-sharing axis; rounds 4 & 17 showed both neighbors regress)
// FIXED-MAX softmax; Q/K/P/T all bf16 hi-only; PV + denominator via 16x16x16
// MFMA on the native QK C/D fragment; T read as b64 sub-frags (half-swapped).
__global__ void __launch_bounds__(512, 4) k_hopfield(
    const u16* __restrict__ Qh,
    const u16* __restrict__ Kh,
    const u16* __restrict__ Kth,
    const u16* __restrict__ Vth,
    u16* __restrict__ Oh, u16* __restrict__ Ol)
{
  __shared__ bf16x8 sKh[2][512], sTh[2][512];
  const int tid = threadIdx.x, lane = tid & 63, w = tid >> 6;
  const int cl = lane & 15, gq = lane >> 4;
  int flat = blockIdx.x;
  flat = (flat & 7)*64 + (flat >> 3);              // XCD swizzle (512 % 8 == 0: bijective)
  const int bh = flat >> 4, qt = flat & 15;
  const size_t base = (size_t)bh * (2048*64);
  const int q = qt*128 + w*16 + cl;

  const int sr = tid >> 3, ss = swz(tid & 7, sr);
  const size_t offK = base + (size_t)sr*64 + ss*8;      // + kt*4096
  const size_t offT = base + (size_t)sr*2048 + ss*8;    // + kt*64
  const int wslot = w << 6;

  bf16x8 qfh[2];
#pragma unroll
  for (int ks = 0; ks < 2; ++ks)
    qfh[ks] = *(const bf16x8*)(Qh + base + (size_t)q*64 + ks*32 + gq*8);

  const int srcA = cl + ((gq & 1) << 5);
  const int srcB = srcA + 16;
  const bool sel_hi = gq >= 2;

  const bf16x4 ones = {(short)0x3F80, (short)0x3F80, (short)0x3F80, (short)0x3F80};
  f32x4 accL = {0,0,0,0};
  f32x4 accO[4] = {};

  GLDS(Kh  + offK, &sKh[0][wslot]);
  GLDS(Kth + offT, &sTh[0][wslot]);
  __syncthreads();

#pragma unroll 2
  for (int t = 0; t < 128; ++t){
    const int cur = t & 1, kt = t & 31;
    if (t < 127){
      const int nt_ = t + 1, nb = nt_ & 1, nit = nt_ >> 5, nkt = nt_ & 31;
      const u16* th = (nit < 3) ? Kth : Vth;
      GLDS(Kh + offK + (size_t)nkt*4096, &sKh[nb][wslot]);
      GLDS(th + offT + (size_t)nkt*64,   &sTh[nb][wslot]);
    }
    f32x4 S[4] = {};
    __builtin_amdgcn_s_setprio(1);
#pragma unroll
    for (int ks = 0; ks < 2; ++ks){
      const int slot = ks*4 + gq;
#pragma unroll
      for (int i = 0; i < 4; ++i){
        bf16x8 kh_ = frag(&sKh[cur][0], i*16 + cl, slot);
        S[i] = __builtin_amdgcn_mfma_f32_16x16x32_bf16(kh_, qfh[ks], S[i], 0, 0, 0);
      }
    }
    __builtin_amdgcn_s_setprio(0);
#pragma unroll
    for (int i = 0; i < 4; ++i)
#pragma unroll
      for (int r = 0; r < 4; ++r)
        S[i][r] = fastexp2(__builtin_fmaf(S[i][r], C1, NEGM));
    bf16x4 pf[4];
#pragma unroll
    for (int a = 0; a < 4; ++a)
      pf[a] = pk4(S[a][0], S[a][1], S[a][2], S[a][3]);
    __builtin_amdgcn_s_setprio(1);
#pragma unroll
    for (int a = 0; a < 4; ++a)
      accL = __builtin_amdgcn_mfma_f32_16x16x16bf16_1k(ones, pf[a], accL, 0, 0, 0);
#pragma unroll
    for (int db = 0; db < 4; ++db)
#pragma unroll
      for (int a = 0; a < 4; ++a){
        bf16x4 vh_ = frag64(&sTh[cur][0], db*16 + cl, 2*a + (gq>>1), gq&1);
        accO[db] = __builtin_amdgcn_mfma_f32_16x16x16bf16_1k(vh_, pf[a], accO[db], 0, 0, 0);
      }
    __builtin_amdgcn_s_setprio(0);
    if (kt == 31){
      const float inv = 1.f / accL[0];
      f32x4 vals[4];
#pragma unroll
      for (int db = 0; db < 4; ++db)
#pragma unroll
        for (int r = 0; r < 4; ++r) vals[db][r] = accO[db][r]*inv;
      if (t < 127){
        exchange_hi(vals, srcA, srcB, sel_hi, qfh[0], qfh[1]);
        accL = f32x4{0,0,0,0};
#pragma unroll
        for (int db = 0; db < 4; ++db) accO[db] = f32x4{0,0,0,0};
      } else {
        const int b = bh >> 4, h = bh & 15;
        const size_t row = (size_t)b*2048 + q;
#pragma unroll
        for (int db = 0; db < 4; ++db){
          u16x4 h4, l4;
#pragma unroll
          for (int r = 0; r < 4; ++r){ u16 a_, b_; fsplit(vals[db][r], a_, b_); h4[r] = a_; l4[r] = b_; }
          size_t ix = row*1024 + h*64 + db*16 + gq*4;
          *(u16x4*)(Oh + ix) = h4;
          *(u16x4*)(Ol + ix) = l4;
        }
      }
    }
    __syncthreads();
  }
}

extern "C" void kernel_launch(void* const* d_in, const int* in_sizes, int n_in,
                              void* d_out, int out_size, void* d_ws, size_t ws_size,
                              hipStream_t stream) {
  (void)in_sizes; (void)n_in; (void)out_size; (void)ws_size;
  const float* query = (const float*)d_in[0];
  const float* key   = (const float*)d_in[1];
  const float* value = (const float*)d_in[2];
  const float* Wq = (const float*)d_in[3];
  const float* bq = (const float*)d_in[4];
  const float* Wk = (const float*)d_in[5];
  const float* bk = (const float*)d_in[6];
  const float* Wv = (const float*)d_in[7];
  const float* bv = (const float*)d_in[8];
  const float* Wo = (const float*)d_in[9];
  const float* bo = (const float*)d_in[10];
  const float* gamma = (const float*)d_in[11];
  const float* beta  = (const float*)d_in[12];
  float* out = (float*)d_out;

  char* ws = (char*)d_ws;
  const size_t MB = 1024*1024;
  u16* inq_h = (u16*)(ws + 0*MB),  *inq_l = (u16*)(ws + 8*MB);
  u16* ink_h = (u16*)(ws + 16*MB);
  u16* inv_h = (u16*)(ws + 32*MB);
  u16* wq_h = (u16*)(ws + 48*MB);
  u16* wk_h = (u16*)(ws + 52*MB);
  u16* wv_h = (u16*)(ws + 56*MB);
  u16* wo_h = (u16*)(ws + 60*MB), *wo_l = (u16*)(ws + 62*MB);
  u16* Qh  = (u16*)(ws + 64*MB);
  u16* Kh  = (u16*)(ws + 80*MB);
  u16* Kth = (u16*)(ws + 96*MB);
  u16* Vth = (u16*)(ws + 112*MB);
  u16* Oh = inq_h, *Ol = inq_l;    // reuse: inq dead after proj

  const int n4 = 4096*1024/4;
  k_split3<<<dim3(1024, 3), dim3(256), 0, stream>>>(query, key, value,
                                                    inq_h, ink_h, inv_h, n4);
  k_wsplit4<<<dim3(32,32,4), dim3(256), 0, stream>>>(Wq, Wk, Wv, Wo,
                                                     wq_h, wk_h, wv_h, wo_h, wo_l);

  k_proj3<<<dim3(16,32,3), dim3(256), 0, stream>>>(inq_h, ink_h, inv_h,
                                                   wq_h, wk_h, wv_h,
                                                   bq, bk, bv, gamma, beta,
                                                   Qh, Kh, Kth, Vth);

  k_hopfield<<<dim3(512), dim3(512), 0, stream>>>(Qh, Kh, Kth, Vth, Oh, Ol);

  k_projo<<<dim3(16,32), dim3(256), 0, stream>>>(Oh, Ol, wo_h, wo_l, bo, out);
}

// Round 19
// 265.089 us; speedup vs baseline: 1.0824x; 1.0215x over previous
//
#include <hip/hip_runtime.h>

typedef unsigned short u16;
typedef __attribute__((ext_vector_type(8))) short bf16x8;
typedef __attribute__((ext_vector_type(4))) short bf16x4;
typedef __attribute__((ext_vector_type(4))) float f32x4;
typedef __attribute__((ext_vector_type(4))) u16 u16x4;

#define C1 0.18033688011112042f   // log2(e)/8  (folds the 1/sqrt(64) score scale)
#define NEGM (-64.0f*C1)          // fixed-max offset in exp2 domain

#define GLDS(g, l) __builtin_amdgcn_global_load_lds( \
    (const __attribute__((address_space(1))) void*)(g), \
    (__attribute__((address_space(3))) void*)(l), 16, 0, 0)

__device__ __forceinline__ float fastexp2(float x){
  float r;
  asm("v_exp_f32 %0, %1" : "=v"(r) : "v"(x));
  return r;
}

// packed f32x2 -> bf16x2 (low16 = bf16(x0), high16 = bf16(x1)), 1 VALU op
__device__ __forceinline__ unsigned cvtpk(float x0, float x1){
  unsigned r;
  asm("v_cvt_pk_bf16_f32 %0, %1, %2" : "=v"(r) : "v"(x0), "v"(x1));
  return r;
}

__device__ __forceinline__ bf16x4 pk4(float x0, float x1, float x2, float x3){
  union { unsigned u[2]; bf16x4 b; } o;
  o.u[0] = cvtpk(x0, x1);
  o.u[1] = cvtpk(x2, x3);
  return o.b;
}

__device__ __forceinline__ u16 f2bf(float x){
  unsigned u = __float_as_uint(x);
  u += 0x7fffu + ((u >> 16) & 1u);
  return (u16)(u >> 16);
}
__device__ __forceinline__ float bf2f(u16 h){ return __uint_as_float(((unsigned)h) << 16); }
__device__ __forceinline__ void fsplit(float x, u16 &h, u16 &l){
  h = f2bf(x);
  l = f2bf(x - bf2f(h));
}

// LDS slot swizzle (involution per row; empirically the low-conflict pattern).
__device__ __forceinline__ int swz(int slot, int r){
  return slot ^ (r & 7);
}

// 8-slot-per-row accessor (128B rows: K tiles, projection tiles)
__device__ __forceinline__ bf16x8 frag(const bf16x8* lds, int r, int slot){
  return lds[r*8 + swz(slot, r)];
}

// 16-slot-per-row b64 accessor (256B rows: KB=128 T tile). Data stored
// half-swapped by row-bit-3 (see T-writes) so quarter-wave lanes cover all
// 32 banks: 16 lanes -> 8 sw values x 2 opposite halves.
__device__ __forceinline__ bf16x4 frag64T(const bf16x8* lds, int r, int slot, int half){
  return ((const bf16x4*)&lds[r*16 + (slot ^ (r & 7))])[half ^ ((r >> 3) & 1)];
}

// GLDS tile staging for 8-slot rows (projection kernels): linear LDS dest,
// inverse-swizzled global source column (rule #21).
template<int ROWS>
__device__ __forceinline__ void stage_glds(bf16x8* lds, const u16* __restrict__ g,
                                           size_t row0, int ldg, int col0, int tid, int w){
#pragma unroll
  for (int p = 0; p < ROWS/32; ++p){
    int idx = p*256 + tid;
    int r = idx >> 3, slot = idx & 7;
    int ss = swz(slot, r);
    GLDS(g + (row0 + (size_t)r)*(size_t)ldg + col0 + ss*8, &lds[p*256 + (w<<6)]);
  }
}

// split-bf16 3-term product: X*Y ~= Xh*Yh + Xh*Yl + Xl*Yh   (fp32 accumulate)
__device__ __forceinline__ f32x4 mfma3(bf16x8 xh, bf16x8 xl, bf16x8 yh, bf16x8 yl, f32x4 c){
  c = __builtin_amdgcn_mfma_f32_16x16x32_bf16(xh, yh, c, 0, 0, 0);
  c = __builtin_amdgcn_mfma_f32_16x16x32_bf16(xh, yl, c, 0, 0, 0);
  c = __builtin_amdgcn_mfma_f32_16x16x32_bf16(xl, yh, c, 0, 0, 0);
  return c;
}

// ---- C/D-layout -> B-fragment relayout via 4-lane shuffle (hi-only) ----------
// (used only for the q-rebuild at iteration ends, 4x per kernel)
__device__ __forceinline__ void exchange_hi(const f32x4* X, int srcA, int srcB, bool sel_hi,
                                            bf16x8& oh0, bf16x8& oh1)
{
  unsigned hi[8];
#pragma unroll
  for (int a = 0; a < 4; ++a)
#pragma unroll
    for (int b0 = 0; b0 < 2; ++b0)
      hi[a*2+b0] = cvtpk(X[a][2*b0], X[a][2*b0+1]);
  unsigned OH[8];
#pragma unroll
  for (int f = 0; f < 8; ++f){
    const int t0 = (f>>2)*4 + (f&1);
    const int sl = ((f&3)>>1) ? srcB : srcA;
    unsigned h0 = (unsigned)__shfl((int)hi[t0],     sl, 64);
    unsigned h2 = (unsigned)__shfl((int)hi[t0 + 2], sl, 64);
    OH[f] = sel_hi ? h2 : h0;
  }
  union U { unsigned u[4]; bf16x8 b; };
  U a0, a1;
#pragma unroll
  for (int c = 0; c < 4; ++c){ a0.u[c]=OH[c]; a1.u[c]=OH[4+c]; }
  oh0=a0.b; oh1=a1.b;
}

// ---------------- elementwise convert (fused over q/k/v): fp32 -> bf16 hi ----------------
__global__ void __launch_bounds__(256) k_split3(
    const float* __restrict__ xq, const float* __restrict__ xk, const float* __restrict__ xv,
    u16* __restrict__ qh, u16* __restrict__ kh, u16* __restrict__ vh, int n4){
  const int which = blockIdx.y;
  const float* x = which == 0 ? xq : which == 1 ? xk : xv;
  u16* hh = which == 0 ? qh : which == 1 ? kh : vh;
  for (int i = blockIdx.x*256 + threadIdx.x; i < n4; i += gridDim.x*256){
    float4 v = ((const float4*)x)[i];
    u16x4 h;
    h[0] = f2bf(v.x); h[1] = f2bf(v.y); h[2] = f2bf(v.z); h[3] = f2bf(v.w);
    *(u16x4*)(hh + (size_t)i*4) = h;
  }
}

// ---------------- weight transpose + split (fused over 4 weights) ----------------
// wq, wk, wv: hi only. wo: hi + lo (out-proj stays 3-term for output precision).
__global__ void __launch_bounds__(256) k_wsplit4(
    const float* __restrict__ W0, const float* __restrict__ W1,
    const float* __restrict__ W2, const float* __restrict__ W3,
    u16* __restrict__ T0h, u16* __restrict__ T1h, u16* __restrict__ T2h,
    u16* __restrict__ T3h, u16* __restrict__ T3l){
  const int which = blockIdx.z;
  const float* W = which == 0 ? W0 : which == 1 ? W1 : which == 2 ? W2 : W3;
  u16* Th = which == 0 ? T0h : which == 1 ? T1h : which == 2 ? T2h : T3h;
  __shared__ float t[32][33];
  int tx = threadIdx.x & 31, ty = threadIdx.x >> 5;      // 32 x 8
  int n0 = blockIdx.x*32, k0 = blockIdx.y*32;
#pragma unroll
  for (int i = 0; i < 4; ++i)
    t[ty + 8*i][tx] = W[(size_t)(k0 + ty + 8*i)*1024 + n0 + tx];
  __syncthreads();
#pragma unroll
  for (int i = 0; i < 4; ++i){
    int n = n0 + ty + 8*i, k = k0 + tx;
    if (which == 3){
      u16 a, b; fsplit(t[tx][ty + 8*i], a, b);
      Th[(size_t)n*1024 + k] = a;
      T3l[(size_t)n*1024 + k] = b;
    } else {
      Th[(size_t)n*1024 + k] = f2bf(t[tx][ty + 8*i]);
    }
  }
}

// ---------------- fused Q/K/V projection GEMMs (one dispatch) ----------------
// blockIdx.z = mode: 0=Q (LN, natural write), 1=K (LN, natural + transposed),
// 2=V (transposed only). 1-term hi*hi, tile 128x64, GLDS staging.
__global__ void __launch_bounds__(256, 3) k_proj3(
    const u16* __restrict__ Aq, const u16* __restrict__ Ak, const u16* __restrict__ Av,
    const u16* __restrict__ Bq, const u16* __restrict__ Bk, const u16* __restrict__ Bv,
    const float* __restrict__ bq, const float* __restrict__ bk, const float* __restrict__ bv_,
    const float* __restrict__ gamma, const float* __restrict__ beta,
    u16* __restrict__ Qh, u16* __restrict__ Kh,
    u16* __restrict__ Kth, u16* __restrict__ Vth)
{
  __shared__ bf16x8 sAh[128*8], sBh[64*8];
  const int mode = blockIdx.z;
  const u16* Ah = mode == 0 ? Aq : mode == 1 ? Ak : Av;
  const u16* Bh = mode == 0 ? Bq : mode == 1 ? Bk : Bv;
  const float* bias = mode == 0 ? bq : mode == 1 ? bk : bv_;
  const int tid = threadIdx.x, lane = tid & 63, w = tid >> 6;
  const int cl = lane & 15, gq = lane >> 4;
  const int nt = blockIdx.x, mt = blockIdx.y;
  f32x4 acc[2][4] = {};
  for (int kt = 0; kt < 16; ++kt){
    __syncthreads();
    stage_glds<128>(sAh, Ah, (size_t)mt*128, 1024, kt*64, tid, w);
    stage_glds<64>(sBh, Bh, (size_t)nt*64, 1024, kt*64, tid, w);
    __syncthreads();
#pragma unroll
    for (int ks = 0; ks < 2; ++ks){
      const int slot = ks*4 + gq;
      bf16x8 ah0 = frag(sAh, w*32 + cl, slot);
      bf16x8 ah1 = frag(sAh, w*32 + 16 + cl, slot);
#pragma unroll
      for (int f = 0; f < 4; ++f){
        bf16x8 bh_ = frag(sBh, f*16 + cl, slot);
        acc[0][f] = __builtin_amdgcn_mfma_f32_16x16x32_bf16(ah0, bh_, acc[0][f], 0, 0, 0);
        acc[1][f] = __builtin_amdgcn_mfma_f32_16x16x32_bf16(ah1, bh_, acc[1][f], 0, 0, 0);
      }
    }
  }
  float bv[4];
#pragma unroll
  for (int f = 0; f < 4; ++f) bv[f] = bias[nt*64 + f*16 + cl];
  float gm[4], bt[4];
  if (mode <= 1){
#pragma unroll
    for (int f = 0; f < 4; ++f){ gm[f] = gamma[f*16 + cl]; bt[f] = beta[f*16 + cl]; }
  }
#pragma unroll
  for (int mi = 0; mi < 2; ++mi){
    float v[4][4];
#pragma unroll
    for (int f = 0; f < 4; ++f)
#pragma unroll
      for (int r = 0; r < 4; ++r) v[f][r] = acc[mi][f][r] + bv[f];
    if (mode <= 1){
#pragma unroll
      for (int r = 0; r < 4; ++r){
        float s1 = v[0][r] + v[1][r] + v[2][r] + v[3][r];
        float s2 = v[0][r]*v[0][r] + v[1][r]*v[1][r] + v[2][r]*v[2][r] + v[3][r]*v[3][r];
#pragma unroll
        for (int d = 1; d < 16; d <<= 1){ s1 += __shfl_xor(s1, d); s2 += __shfl_xor(s2, d); }
        float mu = s1 * (1.f/64.f);
        float var = s2 * (1.f/64.f) - mu*mu;
        float rs = rsqrtf(var + 1e-5f);
#pragma unroll
        for (int f = 0; f < 4; ++f) v[f][r] = (v[f][r] - mu)*rs*gm[f] + bt[f];
      }
    }
    const int mrow = mt*128 + w*32 + mi*16 + gq*4;   // + r
    const int b = mrow >> 11, srow = mrow & 2047;
    const size_t hb = (size_t)(b*16 + nt);            // head-major (b*16 + head)
    if (mode <= 1){                                   // natural write, hi only
      u16* Nh = mode == 0 ? Qh : Kh;
#pragma unroll
      for (int f = 0; f < 4; ++f)
#pragma unroll
        for (int r = 0; r < 4; ++r)
          Nh[(hb*2048 + srow + r)*64 + f*16 + cl] = f2bf(v[f][r]);
    }
    if (mode >= 1){                                   // transposed write, hi only
      u16* Th = mode == 1 ? Kth : Vth;
      const int srow_sw = srow ^ (((cl >> 3) & 1) << 2);
#pragma unroll
      for (int f = 0; f < 4; ++f){
        u16x4 h4;
#pragma unroll
        for (int r = 0; r < 4; ++r) h4[r] = f2bf(v[f][r]);
        *(u16x4*)(Th + (hb*64 + f*16 + cl)*2048 + srow_sw) = h4;
      }
    }
  }
}

// ---------------- output projection GEMM (3-term split) ----------------
__global__ void __launch_bounds__(256, 3) k_projo(
    const u16* __restrict__ Ah, const u16* __restrict__ Al,
    const u16* __restrict__ Bh, const u16* __restrict__ Bl,
    const float* __restrict__ bias,
    float* __restrict__ Fo)
{
  __shared__ bf16x8 sAh[128*8], sAl[128*8], sBh[64*8], sBl[64*8];
  const int tid = threadIdx.x, lane = tid & 63, w = tid >> 6;
  const int cl = lane & 15, gq = lane >> 4;
  const int nt = blockIdx.x, mt = blockIdx.y;
  f32x4 acc[2][4] = {};
  for (int kt = 0; kt < 16; ++kt){
    __syncthreads();
    stage_glds<128>(sAh, Ah, (size_t)mt*128, 1024, kt*64, tid, w);
    stage_glds<64>(sBh, Bh, (size_t)nt*64, 1024, kt*64, tid, w);
    stage_glds<128>(sAl, Al, (size_t)mt*128, 1024, kt*64, tid, w);
    stage_glds<64>(sBl, Bl, (size_t)nt*64, 1024, kt*64, tid, w);
    __syncthreads();
#pragma unroll
    for (int ks = 0; ks < 2; ++ks){
      const int slot = ks*4 + gq;
      bf16x8 ah0 = frag(sAh, w*32 + cl, slot);
      bf16x8 ah1 = frag(sAh, w*32 + 16 + cl, slot);
      bf16x8 al0 = frag(sAl, w*32 + cl, slot);
      bf16x8 al1 = frag(sAl, w*32 + 16 + cl, slot);
#pragma unroll
      for (int f = 0; f < 4; ++f){
        bf16x8 bh_ = frag(sBh, f*16 + cl, slot);
        bf16x8 bl_ = frag(sBl, f*16 + cl, slot);
        acc[0][f] = mfma3(ah0, al0, bh_, bl_, acc[0][f]);
        acc[1][f] = mfma3(ah1, al1, bh_, bl_, acc[1][f]);
      }
    }
  }
  float bv[4];
#pragma unroll
  for (int f = 0; f < 4; ++f) bv[f] = bias[nt*64 + f*16 + cl];
#pragma unroll
  for (int mi = 0; mi < 2; ++mi){
    const int mrow = mt*128 + w*32 + mi*16 + gq*4;
#pragma unroll
    for (int f = 0; f < 4; ++f)
#pragma unroll
      for (int r = 0; r < 4; ++r)
        Fo[(size_t)(mrow + r)*1024 + nt*64 + f*16 + cl] = acc[mi][f][r] + bv[f];
  }
}

// ---------------- fused Hopfield attention: all 4 iterations in one launch ----------------
// 8 waves x 16 q (measured optimum), KB=128: 64 tile-steps (was 128) -> half the
// barrier drains (the 18% per-step overhead), same LDS bytes / MFMA / exp totals.
// K tile [128][64] (8-slot rows, frag); T tile [64][128] (16-slot rows, frag64T,
// half-swapped storage). FIXED-MAX softmax; Q/K/P/T bf16 hi-only; PV + denominator
// via 16x16x16 MFMA on the native QK C/D fragment. LDS 64 KB, 2 blocks/CU.
__global__ void __launch_bounds__(512, 4) k_hopfield(
    const u16* __restrict__ Qh,
    const u16* __restrict__ Kh,
    const u16* __restrict__ Kth,
    const u16* __restrict__ Vth,
    u16* __restrict__ Oh, u16* __restrict__ Ol)
{
  __shared__ bf16x8 sKh[2][1024], sTh[2][1024];
  const int tid = threadIdx.x, lane = tid & 63, w = tid >> 6;
  const int cl = lane & 15, gq = lane >> 4;
  int flat = blockIdx.x;
  flat = (flat & 7)*64 + (flat >> 3);              // XCD swizzle (512 % 8 == 0: bijective)
  const int bh = flat >> 4, qt = flat & 15;
  const size_t base = (size_t)bh * (2048*64);
  const int q = qt*128 + w*16 + cl;

  // staging geometry. K tile: 1024 slots, thread stages idx = tid, tid+512
  // (rows r, r+64; (64+r)&7 == r&7 -> same pre-swizzled column).
  const int krow = tid >> 3, kss = swz(tid & 7, krow);
  const size_t offK = base + (size_t)krow*64 + kss*8;    // + kt*8192 ; +4096 for row+64
  // T tile: 16-slot rows; thread stages idx = tid, tid+512 (rows d, d+32).
  const int trow = tid >> 4, tss = (tid & 15) ^ (trow & 7);
  const size_t offT = base + (size_t)trow*2048 + tss*8;  // + kt*128 ; +65536 for row+32
  const int wslot = w << 6;                              // wave chunk (bf16x8 units)

  bf16x8 qfh[2];
#pragma unroll
  for (int ks = 0; ks < 2; ++ks)
    qfh[ks] = *(const bf16x8*)(Qh + base + (size_t)q*64 + ks*32 + gq*8);

  const int srcA = cl + ((gq & 1) << 5);
  const int srcB = srcA + 16;
  const bool sel_hi = gq >= 2;

  const bf16x4 ones = {(short)0x3F80, (short)0x3F80, (short)0x3F80, (short)0x3F80};
  f32x4 accL = {0,0,0,0};
  f32x4 accO[4] = {};

  // prologue: stage tile 0 (it=0 -> T source is Kt)
  GLDS(Kh  + offK,         &sKh[0][wslot]);
  GLDS(Kh  + offK + 4096,  &sKh[0][wslot + 512]);
  GLDS(Kth + offT,         &sTh[0][wslot]);
  GLDS(Kth + offT + 65536, &sTh[0][wslot + 512]);
  __syncthreads();

#pragma unroll 2
  for (int t = 0; t < 64; ++t){
    const int cur = t & 1, kt = t & 15;
    if (t < 63){
      const int nt_ = t + 1, nb = nt_ & 1, nit = nt_ >> 4, nkt = nt_ & 15;
      const u16* th = (nit < 3) ? Kth : Vth;
      const size_t oK = offK + (size_t)nkt*8192;
      const size_t oT = offT + (size_t)nkt*128;
      GLDS(Kh + oK,         &sKh[nb][wslot]);
      GLDS(Kh + oK + 4096,  &sKh[nb][wslot + 512]);
      GLDS(th + oT,         &sTh[nb][wslot]);
      GLDS(th + oT + 65536, &sTh[nb][wslot + 512]);
    }
    // ---- QK^T: St[kv][q] over 128 kv rows ----
    f32x4 S[8] = {};
    __builtin_amdgcn_s_setprio(1);
#pragma unroll
    for (int ks = 0; ks < 2; ++ks){
      const int slot = ks*4 + gq;
#pragma unroll
      for (int i = 0; i < 8; ++i){
        bf16x8 kh_ = frag(&sKh[cur][0], i*16 + cl, slot);
        S[i] = __builtin_amdgcn_mfma_f32_16x16x32_bf16(kh_, qfh[ks], S[i], 0, 0, 0);
      }
    }
    __builtin_amdgcn_s_setprio(0);
    // ---- fixed-max softmax: p = exp2(S*C1 - 64*C1) ----
#pragma unroll
    for (int i = 0; i < 8; ++i)
#pragma unroll
      for (int r = 0; r < 4; ++r)
        S[i][r] = fastexp2(__builtin_fmaf(S[i][r], C1, NEGM));
    bf16x4 pf[8];
#pragma unroll
    for (int a = 0; a < 8; ++a)
      pf[a] = pk4(S[a][0], S[a][1], S[a][2], S[a][3]);
    // ---- denominator + PV via 16x16x16 (P already in native B-frag layout) ----
    __builtin_amdgcn_s_setprio(1);
#pragma unroll
    for (int a = 0; a < 8; ++a)
      accL = __builtin_amdgcn_mfma_f32_16x16x16bf16_1k(ones, pf[a], accL, 0, 0, 0);
#pragma unroll
    for (int db = 0; db < 4; ++db)
#pragma unroll
      for (int a = 0; a < 8; ++a){
        bf16x4 vh_ = frag64T(&sTh[cur][0], db*16 + cl, 2*a + (gq>>1), gq&1);
        accO[db] = __builtin_amdgcn_mfma_f32_16x16x16bf16_1k(vh_, pf[a], accO[db], 0, 0, 0);
      }
    __builtin_amdgcn_s_setprio(0);
    // ---- iteration epilogue (every 16 steps) ----
    if (kt == 15){
      const float inv = 1.f / accL[0];
      f32x4 vals[4];
#pragma unroll
      for (int db = 0; db < 4; ++db)
#pragma unroll
        for (int r = 0; r < 4; ++r) vals[db][r] = accO[db][r]*inv;
      if (t < 63){
        exchange_hi(vals, srcA, srcB, sel_hi, qfh[0], qfh[1]);
        accL = f32x4{0,0,0,0};
#pragma unroll
        for (int db = 0; db < 4; ++db) accO[db] = f32x4{0,0,0,0};
      } else {
        const int b = bh >> 4, h = bh & 15;
        const size_t row = (size_t)b*2048 + q;
#pragma unroll
        for (int db = 0; db < 4; ++db){
          u16x4 h4, l4;
#pragma unroll
          for (int r = 0; r < 4; ++r){ u16 a_, b_; fsplit(vals[db][r], a_, b_); h4[r] = a_; l4[r] = b_; }
          size_t ix = row*1024 + h*64 + db*16 + gq*4;
          *(u16x4*)(Oh + ix) = h4;
          *(u16x4*)(Ol + ix) = l4;
        }
      }
    }
    __syncthreads();
  }
}

extern "C" void kernel_launch(void* const* d_in, const int* in_sizes, int n_in,
                              void* d_out, int out_size, void* d_ws, size_t ws_size,
                              hipStream_t stream) {
  (void)in_sizes; (void)n_in; (void)out_size; (void)ws_size;
  const float* query = (const float*)d_in[0];
  const float* key   = (const float*)d_in[1];
  const float* value = (const float*)d_in[2];
  const float* Wq = (const float*)d_in[3];
  const float* bq = (const float*)d_in[4];
  const float* Wk = (const float*)d_in[5];
  const float* bk = (const float*)d_in[6];
  const float* Wv = (const float*)d_in[7];
  const float* bv = (const float*)d_in[8];
  const float* Wo = (const float*)d_in[9];
  const float* bo = (const float*)d_in[10];
  const float* gamma = (const float*)d_in[11];
  const float* beta  = (const float*)d_in[12];
  float* out = (float*)d_out;

  char* ws = (char*)d_ws;
  const size_t MB = 1024*1024;
  u16* inq_h = (u16*)(ws + 0*MB),  *inq_l = (u16*)(ws + 8*MB);
  u16* ink_h = (u16*)(ws + 16*MB);
  u16* inv_h = (u16*)(ws + 32*MB);
  u16* wq_h = (u16*)(ws + 48*MB);
  u16* wk_h = (u16*)(ws + 52*MB);
  u16* wv_h = (u16*)(ws + 56*MB);
  u16* wo_h = (u16*)(ws + 60*MB), *wo_l = (u16*)(ws + 62*MB);
  u16* Qh  = (u16*)(ws + 64*MB);
  u16* Kh  = (u16*)(ws + 80*MB);
  u16* Kth = (u16*)(ws + 96*MB);
  u16* Vth = (u16*)(ws + 112*MB);
  u16* Oh = inq_h, *Ol = inq_l;    // reuse: inq dead after proj

  const int n4 = 4096*1024/4;
  k_split3<<<dim3(1024, 3), dim3(256), 0, stream>>>(query, key, value,
                                                    inq_h, ink_h, inv_h, n4);
  k_wsplit4<<<dim3(32,32,4), dim3(256), 0, stream>>>(Wq, Wk, Wv, Wo,
                                                     wq_h, wk_h, wv_h, wo_h, wo_l);

  k_proj3<<<dim3(16,32,3), dim3(256), 0, stream>>>(inq_h, ink_h, inv_h,
                                                   wq_h, wk_h, wv_h,
                                                   bq, bk, bv, gamma, beta,
                                                   Qh, Kh, Kth, Vth);

  k_hopfield<<<dim3(512), dim3(512), 0, stream>>>(Qh, Kh, Kth, Vth, Oh, Ol);

  k_projo<<<dim3(16,32), dim3(256), 0, stream>>>(Oh, Ol, wo_h, wo_l, bo, out);
}

// Round 21
// 265.044 us; speedup vs baseline: 1.0825x; 1.0002x over previous
//
#include <hip/hip_runtime.h>

typedef unsigned short u16;
typedef __attribute__((ext_vector_type(8))) short bf16x8;
typedef __attribute__((ext_vector_type(4))) short bf16x4;
typedef __attribute__((ext_vector_type(4))) float f32x4;
typedef __attribute__((ext_vector_type(4))) u16 u16x4;

#define C1 0.18033688011112042f   // log2(e)/8  (folds the 1/sqrt(64) score scale)
#define NEGM (-64.0f*C1)          // fixed-max offset in exp2 domain

#define GLDS(g, l) __builtin_amdgcn_global_load_lds( \
    (const __attribute__((address_space(1))) void*)(g), \
    (__attribute__((address_space(3))) void*)(l), 16, 0, 0)

__device__ __forceinline__ float fastexp2(float x){
  float r;
  asm("v_exp_f32 %0, %1" : "=v"(r) : "v"(x));
  return r;
}

// packed f32x2 -> bf16x2 (low16 = bf16(x0), high16 = bf16(x1)), 1 VALU op
__device__ __forceinline__ unsigned cvtpk(float x0, float x1){
  unsigned r;
  asm("v_cvt_pk_bf16_f32 %0, %1, %2" : "=v"(r) : "v"(x0), "v"(x1));
  return r;
}

__device__ __forceinline__ bf16x4 pk4(float x0, float x1, float x2, float x3){
  union { unsigned u[2]; bf16x4 b; } o;
  o.u[0] = cvtpk(x0, x1);
  o.u[1] = cvtpk(x2, x3);
  return o.b;
}

__device__ __forceinline__ u16 f2bf(float x){
  unsigned u = __float_as_uint(x);
  u += 0x7fffu + ((u >> 16) & 1u);
  return (u16)(u >> 16);
}
__device__ __forceinline__ float bf2f(u16 h){ return __uint_as_float(((unsigned)h) << 16); }
__device__ __forceinline__ void fsplit(float x, u16 &h, u16 &l){
  h = f2bf(x);
  l = f2bf(x - bf2f(h));
}

// LDS slot swizzle (involution per row; empirically the low-conflict pattern).
__device__ __forceinline__ int swz(int slot, int r){
  return slot ^ (r & 7);
}

// 8-slot-per-row accessor (128B rows: K tiles, projection tiles)
__device__ __forceinline__ bf16x8 frag(const bf16x8* lds, int r, int slot){
  return lds[r*8 + swz(slot, r)];
}

// 16-slot-per-row b64 accessor (256B rows: KB=128 T tile). Data stored
// half-swapped by row-bit-3 (see T-writes) so quarter-wave lanes cover all
// 32 banks: 16 lanes -> 8 sw values x 2 opposite halves.
__device__ __forceinline__ bf16x4 frag64T(const bf16x8* lds, int r, int slot, int half){
  return ((const bf16x4*)&lds[r*16 + (slot ^ (r & 7))])[half ^ ((r >> 3) & 1)];
}

// GLDS tile staging for 8-slot rows (projection kernels): linear LDS dest,
// inverse-swizzled global source column (rule #21).
template<int ROWS>
__device__ __forceinline__ void stage_glds(bf16x8* lds, const u16* __restrict__ g,
                                           size_t row0, int ldg, int col0, int tid, int w){
#pragma unroll
  for (int p = 0; p < ROWS/32; ++p){
    int idx = p*256 + tid;
    int r = idx >> 3, slot = idx & 7;
    int ss = swz(slot, r);
    GLDS(g + (row0 + (size_t)r)*(size_t)ldg + col0 + ss*8, &lds[p*256 + (w<<6)]);
  }
}

// split-bf16 3-term product: X*Y ~= Xh*Yh + Xh*Yl + Xl*Yh   (fp32 accumulate)
__device__ __forceinline__ f32x4 mfma3(bf16x8 xh, bf16x8 xl, bf16x8 yh, bf16x8 yl, f32x4 c){
  c = __builtin_amdgcn_mfma_f32_16x16x32_bf16(xh, yh, c, 0, 0, 0);
  c = __builtin_amdgcn_mfma_f32_16x16x32_bf16(xh, yl, c, 0, 0, 0);
  c = __builtin_amdgcn_mfma_f32_16x16x32_bf16(xl, yh, c, 0, 0, 0);
  return c;
}

// ---- C/D-layout -> B-fragment relayout via 4-lane shuffle (hi-only) ----------
// (used only for the q-rebuild at iteration ends, 4x per kernel)
__device__ __forceinline__ void exchange_hi(const f32x4* X, int srcA, int srcB, bool sel_hi,
                                            bf16x8& oh0, bf16x8& oh1)
{
  unsigned hi[8];
#pragma unroll
  for (int a = 0; a < 4; ++a)
#pragma unroll
    for (int b0 = 0; b0 < 2; ++b0)
      hi[a*2+b0] = cvtpk(X[a][2*b0], X[a][2*b0+1]);
  unsigned OH[8];
#pragma unroll
  for (int f = 0; f < 8; ++f){
    const int t0 = (f>>2)*4 + (f&1);
    const int sl = ((f&3)>>1) ? srcB : srcA;
    unsigned h0 = (unsigned)__shfl((int)hi[t0],     sl, 64);
    unsigned h2 = (unsigned)__shfl((int)hi[t0 + 2], sl, 64);
    OH[f] = sel_hi ? h2 : h0;
  }
  union U { unsigned u[4]; bf16x8 b; };
  U a0, a1;
#pragma unroll
  for (int c = 0; c < 4; ++c){ a0.u[c]=OH[c]; a1.u[c]=OH[4+c]; }
  oh0=a0.b; oh1=a1.b;
}

// ---------------- elementwise convert (fused over q/k/v): fp32 -> bf16 hi ----------------
__global__ void __launch_bounds__(256) k_split3(
    const float* __restrict__ xq, const float* __restrict__ xk, const float* __restrict__ xv,
    u16* __restrict__ qh, u16* __restrict__ kh, u16* __restrict__ vh, int n4){
  const int which = blockIdx.y;
  const float* x = which == 0 ? xq : which == 1 ? xk : xv;
  u16* hh = which == 0 ? qh : which == 1 ? kh : vh;
  for (int i = blockIdx.x*256 + threadIdx.x; i < n4; i += gridDim.x*256){
    float4 v = ((const float4*)x)[i];
    u16x4 h;
    h[0] = f2bf(v.x); h[1] = f2bf(v.y); h[2] = f2bf(v.z); h[3] = f2bf(v.w);
    *(u16x4*)(hh + (size_t)i*4) = h;
  }
}

// ---------------- weight transpose + split (fused over 4 weights) ----------------
// wq, wk, wv: hi only. wo: hi + lo (out-proj stays 3-term for output precision).
__global__ void __launch_bounds__(256) k_wsplit4(
    const float* __restrict__ W0, const float* __restrict__ W1,
    const float* __restrict__ W2, const float* __restrict__ W3,
    u16* __restrict__ T0h, u16* __restrict__ T1h, u16* __restrict__ T2h,
    u16* __restrict__ T3h, u16* __restrict__ T3l){
  const int which = blockIdx.z;
  const float* W = which == 0 ? W0 : which == 1 ? W1 : which == 2 ? W2 : W3;
  u16* Th = which == 0 ? T0h : which == 1 ? T1h : which == 2 ? T2h : T3h;
  __shared__ float t[32][33];
  int tx = threadIdx.x & 31, ty = threadIdx.x >> 5;      // 32 x 8
  int n0 = blockIdx.x*32, k0 = blockIdx.y*32;
#pragma unroll
  for (int i = 0; i < 4; ++i)
    t[ty + 8*i][tx] = W[(size_t)(k0 + ty + 8*i)*1024 + n0 + tx];
  __syncthreads();
#pragma unroll
  for (int i = 0; i < 4; ++i){
    int n = n0 + ty + 8*i, k = k0 + tx;
    if (which == 3){
      u16 a, b; fsplit(t[tx][ty + 8*i], a, b);
      Th[(size_t)n*1024 + k] = a;
      T3l[(size_t)n*1024 + k] = b;
    } else {
      Th[(size_t)n*1024 + k] = f2bf(t[tx][ty + 8*i]);
    }
  }
}

// ---------------- fused Q/K/V projection GEMMs (one dispatch) ----------------
// blockIdx.z = mode: 0=Q (LN, natural write), 1=K (LN, natural + transposed),
// 2=V (transposed only). 1-term hi*hi, tile 128x64, GLDS staging.
__global__ void __launch_bounds__(256, 3) k_proj3(
    const u16* __restrict__ Aq, const u16* __restrict__ Ak, const u16* __restrict__ Av,
    const u16* __restrict__ Bq, const u16* __restrict__ Bk, const u16* __restrict__ Bv,
    const float* __restrict__ bq, const float* __restrict__ bk, const float* __restrict__ bv_,
    const float* __restrict__ gamma, const float* __restrict__ beta,
    u16* __restrict__ Qh, u16* __restrict__ Kh,
    u16* __restrict__ Kth, u16* __restrict__ Vth)
{
  __shared__ bf16x8 sAh[128*8], sBh[64*8];
  const int mode = blockIdx.z;
  const u16* Ah = mode == 0 ? Aq : mode == 1 ? Ak : Av;
  const u16* Bh = mode == 0 ? Bq : mode == 1 ? Bk : Bv;
  const float* bias = mode == 0 ? bq : mode == 1 ? bk : bv_;
  const int tid = threadIdx.x, lane = tid & 63, w = tid >> 6;
  const int cl = lane & 15, gq = lane >> 4;
  const int nt = blockIdx.x, mt = blockIdx.y;
  f32x4 acc[2][4] = {};
  for (int kt = 0; kt < 16; ++kt){
    __syncthreads();
    stage_glds<128>(sAh, Ah, (size_t)mt*128, 1024, kt*64, tid, w);
    stage_glds<64>(sBh, Bh, (size_t)nt*64, 1024, kt*64, tid, w);
    __syncthreads();
#pragma unroll
    for (int ks = 0; ks < 2; ++ks){
      const int slot = ks*4 + gq;
      bf16x8 ah0 = frag(sAh, w*32 + cl, slot);
      bf16x8 ah1 = frag(sAh, w*32 + 16 + cl, slot);
#pragma unroll
      for (int f = 0; f < 4; ++f){
        bf16x8 bh_ = frag(sBh, f*16 + cl, slot);
        acc[0][f] = __builtin_amdgcn_mfma_f32_16x16x32_bf16(ah0, bh_, acc[0][f], 0, 0, 0);
        acc[1][f] = __builtin_amdgcn_mfma_f32_16x16x32_bf16(ah1, bh_, acc[1][f], 0, 0, 0);
      }
    }
  }
  float bv[4];
#pragma unroll
  for (int f = 0; f < 4; ++f) bv[f] = bias[nt*64 + f*16 + cl];
  float gm[4], bt[4];
  if (mode <= 1){
#pragma unroll
    for (int f = 0; f < 4; ++f){ gm[f] = gamma[f*16 + cl]; bt[f] = beta[f*16 + cl]; }
  }
#pragma unroll
  for (int mi = 0; mi < 2; ++mi){
    float v[4][4];
#pragma unroll
    for (int f = 0; f < 4; ++f)
#pragma unroll
      for (int r = 0; r < 4; ++r) v[f][r] = acc[mi][f][r] + bv[f];
    if (mode <= 1){
#pragma unroll
      for (int r = 0; r < 4; ++r){
        float s1 = v[0][r] + v[1][r] + v[2][r] + v[3][r];
        float s2 = v[0][r]*v[0][r] + v[1][r]*v[1][r] + v[2][r]*v[2][r] + v[3][r]*v[3][r];
#pragma unroll
        for (int d = 1; d < 16; d <<= 1){ s1 += __shfl_xor(s1, d); s2 += __shfl_xor(s2, d); }
        float mu = s1 * (1.f/64.f);
        float var = s2 * (1.f/64.f) - mu*mu;
        float rs = rsqrtf(var + 1e-5f);
#pragma unroll
        for (int f = 0; f < 4; ++f) v[f][r] = (v[f][r] - mu)*rs*gm[f] + bt[f];
      }
    }
    const int mrow = mt*128 + w*32 + mi*16 + gq*4;   // + r
    const int b = mrow >> 11, srow = mrow & 2047;
    const size_t hb = (size_t)(b*16 + nt);            // head-major (b*16 + head)
    if (mode <= 1){                                   // natural write, hi only
      u16* Nh = mode == 0 ? Qh : Kh;
#pragma unroll
      for (int f = 0; f < 4; ++f)
#pragma unroll
        for (int r = 0; r < 4; ++r)
          Nh[(hb*2048 + srow + r)*64 + f*16 + cl] = f2bf(v[f][r]);
    }
    if (mode >= 1){                                   // transposed write, hi only
      u16* Th = mode == 1 ? Kth : Vth;
      const int srow_sw = srow ^ (((cl >> 3) & 1) << 2);
#pragma unroll
      for (int f = 0; f < 4; ++f){
        u16x4 h4;
#pragma unroll
        for (int r = 0; r < 4; ++r) h4[r] = f2bf(v[f][r]);
        *(u16x4*)(Th + (hb*64 + f*16 + cl)*2048 + srow_sw) = h4;
      }
    }
  }
}

// ---------------- output projection GEMM (3-term split) ----------------
__global__ void __launch_bounds__(256, 3) k_projo(
    const u16* __restrict__ Ah, const u16* __restrict__ Al,
    const u16* __restrict__ Bh, const u16* __restrict__ Bl,
    const float* __restrict__ bias,
    float* __restrict__ Fo)
{
  __shared__ bf16x8 sAh[128*8], sAl[128*8], sBh[64*8], sBl[64*8];
  const int tid = threadIdx.x, lane = tid & 63, w = tid >> 6;
  const int cl = lane & 15, gq = lane >> 4;
  const int nt = blockIdx.x, mt = blockIdx.y;
  f32x4 acc[2][4] = {};
  for (int kt = 0; kt < 16; ++kt){
    __syncthreads();
    stage_glds<128>(sAh, Ah, (size_t)mt*128, 1024, kt*64, tid, w);
    stage_glds<64>(sBh, Bh, (size_t)nt*64, 1024, kt*64, tid, w);
    stage_glds<128>(sAl, Al, (size_t)mt*128, 1024, kt*64, tid, w);
    stage_glds<64>(sBl, Bl, (size_t)nt*64, 1024, kt*64, tid, w);
    __syncthreads();
#pragma unroll
    for (int ks = 0; ks < 2; ++ks){
      const int slot = ks*4 + gq;
      bf16x8 ah0 = frag(sAh, w*32 + cl, slot);
      bf16x8 ah1 = frag(sAh, w*32 + 16 + cl, slot);
      bf16x8 al0 = frag(sAl, w*32 + cl, slot);
      bf16x8 al1 = frag(sAl, w*32 + 16 + cl, slot);
#pragma unroll
      for (int f = 0; f < 4; ++f){
        bf16x8 bh_ = frag(sBh, f*16 + cl, slot);
        bf16x8 bl_ = frag(sBl, f*16 + cl, slot);
        acc[0][f] = mfma3(ah0, al0, bh_, bl_, acc[0][f]);
        acc[1][f] = mfma3(ah1, al1, bh_, bl_, acc[1][f]);
      }
    }
  }
  float bv[4];
#pragma unroll
  for (int f = 0; f < 4; ++f) bv[f] = bias[nt*64 + f*16 + cl];
#pragma unroll
  for (int mi = 0; mi < 2; ++mi){
    const int mrow = mt*128 + w*32 + mi*16 + gq*4;
#pragma unroll
    for (int f = 0; f < 4; ++f)
#pragma unroll
      for (int r = 0; r < 4; ++r)
        Fo[(size_t)(mrow + r)*1024 + nt*64 + f*16 + cl] = acc[mi][f][r] + bv[f];
  }
}

// ---------------- fused Hopfield attention: all 4 iterations in one launch ----------------
// 8 waves x 16 q (measured optimum), KB=128: 64 tile-steps -> half the barrier
// drains, same LDS bytes / MFMA / exp totals. K tile [128][64] (8-slot rows,
// frag); T tile [64][128] (16-slot rows, frag64T, half-swapped storage).
// FIXED-MAX softmax; Q/K/P/T bf16 hi-only; PV + denominator via 16x16x16 MFMA
// on the native QK C/D fragment. LDS 64 KB, 2 blocks/CU.
__global__ void __launch_bounds__(512, 4) k_hopfield(
    const u16* __restrict__ Qh,
    const u16* __restrict__ Kh,
    const u16* __restrict__ Kth,
    const u16* __restrict__ Vth,
    u16* __restrict__ Oh, u16* __restrict__ Ol)
{
  __shared__ bf16x8 sKh[2][1024], sTh[2][1024];
  const int tid = threadIdx.x, lane = tid & 63, w = tid >> 6;
  const int cl = lane & 15, gq = lane >> 4;
  int flat = blockIdx.x;
  flat = (flat & 7)*64 + (flat >> 3);              // XCD swizzle (512 % 8 == 0: bijective)
  const int bh = flat >> 4, qt = flat & 15;
  const size_t base = (size_t)bh * (2048*64);
  const int q = qt*128 + w*16 + cl;

  // staging geometry. K tile: 1024 slots, thread stages idx = tid, tid+512
  // (rows r, r+64; (64+r)&7 == r&7 -> same pre-swizzled column).
  const int krow = tid >> 3, kss = swz(tid & 7, krow);
  const size_t offK = base + (size_t)krow*64 + kss*8;    // + kt*8192 ; +4096 for row+64
  // T tile: 16-slot rows; thread stages idx = tid, tid+512 (rows d, d+32).
  const int trow = tid >> 4, tss = (tid & 15) ^ (trow & 7);
  const size_t offT = base + (size_t)trow*2048 + tss*8;  // + kt*128 ; +65536 for row+32
  const int wslot = w << 6;                              // wave chunk (bf16x8 units)

  bf16x8 qfh[2];
#pragma unroll
  for (int ks = 0; ks < 2; ++ks)
    qfh[ks] = *(const bf16x8*)(Qh + base + (size_t)q*64 + ks*32 + gq*8);

  const int srcA = cl + ((gq & 1) << 5);
  const int srcB = srcA + 16;
  const bool sel_hi = gq >= 2;

  const bf16x4 ones = {(short)0x3F80, (short)0x3F80, (short)0x3F80, (short)0x3F80};
  f32x4 accL = {0,0,0,0};
  f32x4 accO[4] = {};

  // prologue: stage tile 0 (it=0 -> T source is Kt)
  GLDS(Kh  + offK,         &sKh[0][wslot]);
  GLDS(Kh  + offK + 4096,  &sKh[0][wslot + 512]);
  GLDS(Kth + offT,         &sTh[0][wslot]);
  GLDS(Kth + offT + 65536, &sTh[0][wslot + 512]);
  __syncthreads();

#pragma unroll 2
  for (int t = 0; t < 64; ++t){
    const int cur = t & 1, kt = t & 15;
    if (t < 63){
      const int nt_ = t + 1, nb = nt_ & 1, nit = nt_ >> 4, nkt = nt_ & 15;
      const u16* th = (nit < 3) ? Kth : Vth;
      const size_t oK = offK + (size_t)nkt*8192;
      const size_t oT = offT + (size_t)nkt*128;
      GLDS(Kh + oK,         &sKh[nb][wslot]);
      GLDS(Kh + oK + 4096,  &sKh[nb][wslot + 512]);
      GLDS(th + oT,         &sTh[nb][wslot]);
      GLDS(th + oT + 65536, &sTh[nb][wslot + 512]);
    }
    // ---- QK^T: St[kv][q] over 128 kv rows ----
    f32x4 S[8] = {};
    __builtin_amdgcn_s_setprio(1);
#pragma unroll
    for (int ks = 0; ks < 2; ++ks){
      const int slot = ks*4 + gq;
#pragma unroll
      for (int i = 0; i < 8; ++i){
        bf16x8 kh_ = frag(&sKh[cur][0], i*16 + cl, slot);
        S[i] = __builtin_amdgcn_mfma_f32_16x16x32_bf16(kh_, qfh[ks], S[i], 0, 0, 0);
      }
    }
    __builtin_amdgcn_s_setprio(0);
    // ---- fixed-max softmax: p = exp2(S*C1 - 64*C1) ----
#pragma unroll
    for (int i = 0; i < 8; ++i)
#pragma unroll
      for (int r = 0; r < 4; ++r)
        S[i][r] = fastexp2(__builtin_fmaf(S[i][r], C1, NEGM));
    bf16x4 pf[8];
#pragma unroll
    for (int a = 0; a < 8; ++a)
      pf[a] = pk4(S[a][0], S[a][1], S[a][2], S[a][3]);
    // ---- denominator + PV via 16x16x16 (P already in native B-frag layout) ----
    __builtin_amdgcn_s_setprio(1);
#pragma unroll
    for (int a = 0; a < 8; ++a)
      accL = __builtin_amdgcn_mfma_f32_16x16x16bf16_1k(ones, pf[a], accL, 0, 0, 0);
#pragma unroll
    for (int db = 0; db < 4; ++db)
#pragma unroll
      for (int a = 0; a < 8; ++a){
        bf16x4 vh_ = frag64T(&sTh[cur][0], db*16 + cl, 2*a + (gq>>1), gq&1);
        accO[db] = __builtin_amdgcn_mfma_f32_16x16x16bf16_1k(vh_, pf[a], accO[db], 0, 0, 0);
      }
    __builtin_amdgcn_s_setprio(0);
    // ---- iteration epilogue (every 16 steps) ----
    if (kt == 15){
      const float inv = 1.f / accL[0];
      f32x4 vals[4];
#pragma unroll
      for (int db = 0; db < 4; ++db)
#pragma unroll
        for (int r = 0; r < 4; ++r) vals[db][r] = accO[db][r]*inv;
      if (t < 63){
        exchange_hi(vals, srcA, srcB, sel_hi, qfh[0], qfh[1]);
        accL = f32x4{0,0,0,0};
#pragma unroll
        for (int db = 0; db < 4; ++db) accO[db] = f32x4{0,0,0,0};
      } else {
        const int b = bh >> 4, h = bh & 15;
        const size_t row = (size_t)b*2048 + q;
#pragma unroll
        for (int db = 0; db < 4; ++db){
          u16x4 h4, l4;
#pragma unroll
          for (int r = 0; r < 4; ++r){ u16 a_, b_; fsplit(vals[db][r], a_, b_); h4[r] = a_; l4[r] = b_; }
          size_t ix = row*1024 + h*64 + db*16 + gq*4;
          *(u16x4*)(Oh + ix) = h4;
          *(u16x4*)(Ol + ix) = l4;
        }
      }
    }
    __syncthreads();
  }
}

extern "C" void kernel_launch(void* const* d_in, const int* in_sizes, int n_in,
                              void* d_out, int out_size, void* d_ws, size_t ws_size,
                              hipStream_t stream) {
  (void)in_sizes; (void)n_in; (void)out_size; (void)ws_size;
  const float* query = (const float*)d_in[0];
  const float* key   = (const float*)d_in[1];
  const float* value = (const float*)d_in[2];
  const float* Wq = (const float*)d_in[3];
  const float* bq = (const float*)d_in[4];
  const float* Wk = (const float*)d_in[5];
  const float* bk = (const float*)d_in[6];
  const float* Wv = (const float*)d_in[7];
  const float* bv = (const float*)d_in[8];
  const float* Wo = (const float*)d_in[9];
  const float* bo = (const float*)d_in[10];
  const float* gamma = (const float*)d_in[11];
  const float* beta  = (const float*)d_in[12];
  float* out = (float*)d_out;

  char* ws = (char*)d_ws;
  const size_t MB = 1024*1024;
  u16* inq_h = (u16*)(ws + 0*MB),  *inq_l = (u16*)(ws + 8*MB);
  u16* ink_h = (u16*)(ws + 16*MB);
  u16* inv_h = (u16*)(ws + 32*MB);
  u16* wq_h = (u16*)(ws + 48*MB);
  u16* wk_h = (u16*)(ws + 52*MB);
  u16* wv_h = (u16*)(ws + 56*MB);
  u16* wo_h = (u16*)(ws + 60*MB), *wo_l = (u16*)(ws + 62*MB);
  u16* Qh  = (u16*)(ws + 64*MB);
  u16* Kh  = (u16*)(ws + 80*MB);
  u16* Kth = (u16*)(ws + 96*MB);
  u16* Vth = (u16*)(ws + 112*MB);
  u16* Oh = inq_h, *Ol = inq_l;    // reuse: inq dead after proj

  const int n4 = 4096*1024/4;
  k_split3<<<dim3(1024, 3), dim3(256), 0, stream>>>(query, key, value,
                                                    inq_h, ink_h, inv_h, n4);
  k_wsplit4<<<dim3(32,32,4), dim3(256), 0, stream>>>(Wq, Wk, Wv, Wo,
                                                     wq_h, wk_h, wv_h, wo_h, wo_l);

  k_proj3<<<dim3(16,32,3), dim3(256), 0, stream>>>(inq_h, ink_h, inv_h,
                                                   wq_h, wk_h, wv_h,
                                                   bq, bk, bv, gamma, beta,
                                                   Qh, Kh, Kth, Vth);

  k_hopfield<<<dim3(512), dim3(512), 0, stream>>>(Qh, Kh, Kth, Vth, Oh, Ol);

  k_projo<<<dim3(16,32), dim3(256), 0, stream>>>(Oh, Ol, wo_h, wo_l, bo, out);
}